// Round 17
// baseline (277.712 us; speedup 1.0000x reference)
//
#include <hip/hip_runtime.h>

#define N_NODES  50000
#define N_EDGES  600000
#define DIM      128
#define N_LAYERS 5
#define N_GRAPHS 512
#define NB       ((N_NODES + 255) / 256)   // 196
#define NRANGE   16
#define RSPAN    3125                      // 16 * 3125 = 50000
#define NCHUNK   64
#define ESPAN    9375                      // 64 * 9375 = 600000
#define NHB      (NRANGE * NCHUNK)         // 1024 hist/fill blocks
#define BGEMM    782                       // 64-row MFMA tiles

typedef __attribute__((ext_vector_type(8))) short short8;
typedef __attribute__((ext_vector_type(4))) float f32x4;

// bf16 <-> f32 bit helpers (RNE)
__device__ __forceinline__ unsigned short f2b(float f) {
    unsigned u = __float_as_uint(f);
    return (unsigned short)((u + 0x7FFFu + ((u >> 16) & 1u)) >> 16);
}
__device__ __forceinline__ float b2f(short s) {
    return __uint_as_float(((unsigned)(unsigned short)s) << 16);
}
__device__ __forceinline__ float4 b2f4(ushort4 u) {
    float4 c;
    c.x = __uint_as_float((unsigned)u.x << 16);
    c.y = __uint_as_float((unsigned)u.y << 16);
    c.z = __uint_as_float((unsigned)u.z << 16);
    c.w = __uint_as_float((unsigned)u.w << 16);
    return c;
}

// ---------------------------------------------------------------- GEMM body (shared)
// t(bf16) = hin(bf16) @ W_hi, one 64-row tile. Whl = 32KB fragment-ordered LDS.
// Layouts (guide §3): A row=lane&15, k=(lane>>4)*8+j; B col=lane&15, same k;
// C/D col=lane&15, row=(lane>>4)*4+reg.
__device__ __forceinline__ void gemm_tile(const unsigned short* __restrict__ hin,
                                          const unsigned short* __restrict__ wh,
                                          unsigned short* __restrict__ t,
                                          short* Whl, int tile, int tid) {
    const int wv   = tid >> 6;
    const int lane = tid & 63;
    const int rb   = tile * 64;

    {   // stage W_hi (2048 float4, coalesced, 8/thread)
        const float4* GH = (const float4*)wh;
        float4* SH = (float4*)Whl;
#pragma unroll
        for (int i = 0; i < 8; ++i) SH[tid + i * 256] = GH[tid + i * 256];
    }

    int rowA = rb + wv * 16 + (lane & 15);
    if (rowA > N_NODES - 1) rowA = N_NODES - 1;   // clamp loads; store guarded
    const unsigned short* Ab = hin + (size_t)rowA * DIM + (lane >> 4) * 8;
    short8 a[4];
#pragma unroll
    for (int ks = 0; ks < 4; ++ks)
        a[ks] = *(const short8*)(Ab + ks * 32);

    __syncthreads();   // W staged

    f32x4 acc[8] = {};
    const short8* WH = (const short8*)Whl;
#pragma unroll
    for (int nt = 0; nt < 8; ++nt) {
#pragma unroll
        for (int ks = 0; ks < 4; ++ks) {
            short8 bh = WH[(nt * 4 + ks) * 64 + lane];
            acc[nt] = __builtin_amdgcn_mfma_f32_16x16x32_bf16(a[ks], bh, acc[nt], 0, 0, 0);
        }
    }

    const int rowC = rb + wv * 16 + (lane >> 4) * 4;
    const int cl   = lane & 15;
#pragma unroll
    for (int nt = 0; nt < 8; ++nt) {
#pragma unroll
        for (int r = 0; r < 4; ++r) {
            int row = rowC + r;
            if (row < N_NODES)
                t[(size_t)row * DIM + nt * 16 + cl] = f2b(acc[nt][r]);
        }
    }
}

// ---------------------------------------------------------------- preprocess
// Fused dispatch 1: blocks [0,NHB) LDS-histogram; [NHB,NHB+40) W->bf16 frag;
// [NHB+40, +1024) x->bf16. All independent.
__global__ __launch_bounds__(256) void k_prep_hist(const float* __restrict__ x,
                                                   const float* __restrict__ W,
                                                   unsigned short* __restrict__ xb,
                                                   unsigned short* __restrict__ wh,
                                                   const int* __restrict__ dst,
                                                   unsigned short* __restrict__ partial,
                                                   unsigned* __restrict__ gstart,
                                                   unsigned* __restrict__ gend) {
    __shared__ int histo[RSPAN];
    if (blockIdx.x < NHB) {
        const int r  = blockIdx.x & 15;
        const int c  = blockIdx.x >> 4;
        const int lo = r * RSPAN;
        for (int i = threadIdx.x; i < RSPAN; i += 256) histo[i] = 0;
        if (blockIdx.x == 0) {
            for (int i = threadIdx.x; i < N_GRAPHS; i += 256) { gstart[i] = 0u; gend[i] = 0u; }
        }
        __syncthreads();
        const int e0 = c * ESPAN;
        for (int e = e0 + threadIdx.x; e < e0 + ESPAN; e += 256) {
            int d = dst[e] - lo;
            if ((unsigned)d < (unsigned)RSPAN) atomicAdd(&histo[d], 1);
        }
        __syncthreads();
        unsigned short* p = partial + (size_t)(c * NRANGE + r) * RSPAN;
        for (int i = threadIdx.x; i < RSPAN; i += 256) p[i] = (unsigned short)histo[i];
    } else if (blockIdx.x < NHB + 40) {
        // W[5][128][128] f32 -> fragment order: ((nt*4+ks)*64+lane)*8+j,
        // k = ks*32 + (lane>>4)*8 + j, n = nt*16 + (lane&15)
        int t = (blockIdx.x - NHB) * 256 + threadIdx.x;   // < 10240 exactly
        int lane = t & 63;
        int ks   = (t >> 6) & 3;
        int nt   = (t >> 8) & 7;
        int l    = t >> 11;
        int n  = nt * 16 + (lane & 15);
        int kb = ks * 32 + (lane >> 4) * 8;
        size_t obase = (size_t)t * 8;
#pragma unroll
        for (int j = 0; j < 8; ++j) {
            float f = W[(size_t)l * 16384 + (kb + j) * DIM + n];
            wh[obase + j] = f2b(f);
        }
    } else {
        const int total = N_NODES * 32;                   // float4 groups
        for (int t = (blockIdx.x - NHB - 40) * 256 + threadIdx.x; t < total;
             t += 1024 * 256) {
            float4 v = ((const float4*)x)[t];
            ushort4 o;
            o.x = f2b(v.x); o.y = f2b(v.y); o.z = f2b(v.z); o.w = f2b(v.w);
            ((ushort4*)xb)[t] = o;
        }
    }
}

// per node: cnt = sum over chunks (in-place exclusive chunk-prefix), dinv,
// graph ranges (sorted-batch boundaries), fused per-block sum -> bsum.
__global__ __launch_bounds__(256) void k_colsum(unsigned short* __restrict__ partial,
                                                const int* __restrict__ batch,
                                                int* __restrict__ cnt,
                                                float* __restrict__ dinv,
                                                unsigned* __restrict__ gstart,
                                                unsigned* __restrict__ gend,
                                                int* __restrict__ bsum) {
    __shared__ int ws[4];
    int i = blockIdx.x * 256 + threadIdx.x;
    const int inb = (i < N_NODES);
    int sum = 0;
    if (inb) {
        int r  = i / RSPAN;
        int li = i - r * RSPAN;
#pragma unroll 4
        for (int c = 0; c < NCHUNK; ++c) {
            unsigned short* p = partial + (size_t)(c * NRANGE + r) * RSPAN + li;
            int v = *p;
            *p = (unsigned short)sum;     // exclusive prefix over chunks (fits u16)
            sum += v;
        }
    }
    int v = sum;
#pragma unroll
    for (int o = 32; o > 0; o >>= 1) v += __shfl_down(v, o, 64);
    if ((threadIdx.x & 63) == 0) ws[threadIdx.x >> 6] = v;
    __syncthreads();
    if (threadIdx.x == 0) bsum[blockIdx.x] = ws[0] + ws[1] + ws[2] + ws[3];

    if (inb) {
        cnt[i]  = sum;
        dinv[i] = rsqrtf((float)(sum + 1));   // +1 self-loop
        int b = batch[i];
        if (i == 0) gstart[b] = 0u;
        else {
            int pb = batch[i - 1];
            if (b != pb) { gstart[b] = (unsigned)i; gend[pb] = (unsigned)i; }
        }
        if (i == N_NODES - 1) gend[b] = (unsigned)N_NODES;
    }
}

// row_ptr: each block redundantly scans the 196 block sums (cheap), then
// scans its own 256 cnt values. Replaces the separate k_scan_bsum dispatch.
__global__ __launch_bounds__(256) void k_rowptr(const int* __restrict__ cnt,
                                                const int* __restrict__ bsum,
                                                int* __restrict__ row_ptr) {
    __shared__ int sb[256];
    __shared__ int s[256];
    int t = threadIdx.x;
    int bv = (t < NB) ? bsum[t] : 0;
    sb[t] = bv;
    __syncthreads();
    for (int o = 1; o < 256; o <<= 1) {
        int u = (t >= o) ? sb[t - o] : 0;
        __syncthreads();
        sb[t] += u;
        __syncthreads();
    }
    int i = blockIdx.x * 256 + t;
    int v = (i < N_NODES) ? cnt[i] : 0;
    s[t] = v;
    __syncthreads();
    for (int o = 1; o < 256; o <<= 1) {
        int u = (t >= o) ? s[t - o] : 0;
        __syncthreads();
        s[t] += u;
        __syncthreads();
    }
    int boffblk = sb[blockIdx.x] - bsum[blockIdx.x];   // exclusive block offset
    int excl = boffblk + s[t] - v;
    if (i < N_NODES)       row_ptr[i] = excl;
    else if (i == N_NODES) row_ptr[N_NODES] = excl;
}

// Fused dispatch 4: blocks [0,NHB) CSR fill -- col ONLY (wnorm recomputed in
// agg from dinv; bitwise-identical product order). One scattered store per
// edge, no dl staging. Blocks [NHB, NHB+BGEMM): layer-0 GEMM.
__global__ __launch_bounds__(256, 2) void k_fill_gemm(const int* __restrict__ src,
                                                      const int* __restrict__ dst,
                                                      const unsigned short* __restrict__ partial,
                                                      const int* __restrict__ row_ptr,
                                                      int* __restrict__ col,
                                                      const unsigned short* __restrict__ hin,
                                                      const unsigned short* __restrict__ wh,
                                                      unsigned short* __restrict__ t) {
    __shared__ char smem[32768];
    const int tid = threadIdx.x;
    if (blockIdx.x < NHB) {
        int* lcur = (int*)smem;                 // 12.5KB
        const int r  = blockIdx.x & 15;
        const int c  = blockIdx.x >> 4;
        const int lo = r * RSPAN;
        const unsigned short* pp = partial + (size_t)(c * NRANGE + r) * RSPAN;
        for (int i = tid; i < RSPAN; i += 256)
            lcur[i] = row_ptr[lo + i] + (int)pp[i];
        __syncthreads();
        const int e0 = c * ESPAN;
        for (int e = e0 + tid; e < e0 + ESPAN; e += 256) {
            int d = dst[e] - lo;
            int s = src[e];
            if ((unsigned)d < (unsigned)RSPAN) {
                int pos = atomicAdd(&lcur[d], 1);
                col[pos] = s;
            }
        }
    } else {
        gemm_tile(hin, wh, t, (short*)smem, blockIdx.x - NHB, tid);
    }
}

// ---------------------------------------------------------------- transform (MFMA) + hidden pool
__global__ __launch_bounds__(256, 2) void k_gemm_pool(const unsigned short* __restrict__ hin,
                                                      const unsigned short* __restrict__ wh,
                                                      unsigned short* __restrict__ t,
                                                      const unsigned* __restrict__ gstart,
                                                      const unsigned* __restrict__ gend,
                                                      float* __restrict__ out,
                                                      int poolLayer) {
    __shared__ char smem[32768];
    const int tid = threadIdx.x;
    if (blockIdx.x < BGEMM) {
        gemm_tile(hin, wh, t, (short*)smem, blockIdx.x, tid);
    } else {
        float4* red = (float4*)smem;   // [8][32]
        const int g    = blockIdx.x - BGEMM;
        const int slot = tid & 31;
        const int way  = tid >> 5;
        unsigned s = gstart[g], e = gend[g];
        float4 sum = make_float4(0.f, 0.f, 0.f, 0.f);
        for (unsigned i = s + way; i < e; i += 8) {
            float4 v = b2f4(((const ushort4*)hin)[(size_t)i * 32 + slot]);
            sum.x += v.x; sum.y += v.y; sum.z += v.z; sum.w += v.w;
        }
        red[way * 32 + slot] = sum;
        __syncthreads();
        if (tid < 32) {
            float4 tt = red[slot];
#pragma unroll
            for (int wy = 1; wy < 8; ++wy) {
                float4 v = red[wy * 32 + slot];
                tt.x += v.x; tt.y += v.y; tt.z += v.z; tt.w += v.w;
            }
            *(float4*)&out[(size_t)g * (N_LAYERS * DIM) + poolLayer * DIM + slot * 4] = tt;
        }
    }
}

// ---------------------------------------------------------------- aggregation
// hout(bf16) = relu( gather(t, bf16) + bias ). Quarter-wave per node: 16
// lanes x short8 (16B) = 256B row; 4 nodes/wave. Edge weight computed on the
// fly: wt = dinv[j] * dinv[node] (same operand order as the old fill ->
// bitwise identical to the precomputed-wnorm version).
__global__ __launch_bounds__(256) void k_agg_t(const unsigned short* __restrict__ t,
                                               const float* __restrict__ bias,
                                               unsigned short* __restrict__ hout,
                                               const float* __restrict__ dinv,
                                               const int* __restrict__ row_ptr,
                                               const int* __restrict__ col) {
    const int node = blockIdx.x * 16 + (threadIdx.x >> 4);   // 3125*16 = 50000
    const int slot = threadIdx.x & 15;
    const short8* __restrict__ t8 = (const short8*)t + slot;

    float di = dinv[node];
    float dii = di * di;
    short8 v = t8[(size_t)node * 16];
    float acc[8];
#pragma unroll
    for (int j = 0; j < 8; ++j) acc[j] = b2f(v[j]) * dii;    // self-loop

    int e0 = row_ptr[node], e1 = row_ptr[node + 1];
    const int last = e1 - 1;
    for (int e = e0; e < e1; e += 8) {
        int jj[8]; float wt[8];
#pragma unroll
        for (int i = 0; i < 8; ++i) {
            int ee = e + i;
            int cl = (ee <= last) ? ee : last;
            jj[i] = col[cl];
        }
#pragma unroll
        for (int i = 0; i < 8; ++i)
            wt[i] = (e + i <= last) ? dinv[jj[i]] * di : 0.f;
        short8 u[8];
#pragma unroll
        for (int i = 0; i < 8; ++i) u[i] = t8[(size_t)jj[i] * 16];
#pragma unroll
        for (int i = 0; i < 8; ++i)
#pragma unroll
            for (int j = 0; j < 8; ++j)
                acc[j] += b2f(u[i][j]) * wt[i];
    }

    const float* bp = bias + slot * 8;
    short8 o;
#pragma unroll
    for (int j = 0; j < 8; ++j)
        o[j] = (short)f2b(fmaxf(acc[j] + bp[j], 0.f));
    ((short8*)hout)[(size_t)node * 16 + slot] = o;
}

// ---------------------------------------------------------------- standalone pool (last layer)
__global__ __launch_bounds__(512) void k_pool_b(const unsigned short* __restrict__ h,
                                                const unsigned* __restrict__ gstart,
                                                const unsigned* __restrict__ gend,
                                                float* __restrict__ out, int layer) {
    __shared__ float4 red[16][32];
    int g    = blockIdx.x;
    int slot = threadIdx.x & 31;
    int way  = threadIdx.x >> 5;
    unsigned s = gstart[g], e = gend[g];
    float4 sum = make_float4(0.f, 0.f, 0.f, 0.f);
    for (unsigned i = s + way; i < e; i += 16) {
        float4 v = b2f4(((const ushort4*)h)[(size_t)i * 32 + slot]);
        sum.x += v.x; sum.y += v.y; sum.z += v.z; sum.w += v.w;
    }
    red[way][slot] = sum;
    __syncthreads();
    if (threadIdx.x < 32) {
        float4 t = red[0][slot];
#pragma unroll
        for (int wy = 1; wy < 16; ++wy) {
            float4 v = red[wy][slot];
            t.x += v.x; t.y += v.y; t.z += v.z; t.w += v.w;
        }
        *(float4*)&out[(size_t)g * (N_LAYERS * DIM) + layer * DIM + slot * 4] = t;
    }
}

// ---------------------------------------------------------------- launch

extern "C" void kernel_launch(void* const* d_in, const int* in_sizes, int n_in,
                              void* d_out, int out_size, void* d_ws, size_t ws_size,
                              hipStream_t stream) {
    const float* x    = (const float*)d_in[0];
    const int*   ei   = (const int*)d_in[1];
    const int*   bat  = (const int*)d_in[2];
    const float* Ws   = (const float*)d_in[3];
    const float* bs   = (const float*)d_in[4];
    float*       outp = (float*)d_out;

    const int* srcp = ei;
    const int* dstp = ei + N_EDGES;

    char* base = (char*)d_ws;
    size_t off = 0;
    unsigned short* xb      = (unsigned short*)(base + off); off += (size_t)N_NODES * DIM * 2;
    unsigned short* tB      = (unsigned short*)(base + off); off += (size_t)N_NODES * DIM * 2;
    unsigned short* hB0     = (unsigned short*)(base + off); off += (size_t)N_NODES * DIM * 2;
    unsigned short* hB1     = (unsigned short*)(base + off); off += (size_t)N_NODES * DIM * 2;
    float*          dinv    = (float*)(base + off);          off += (size_t)N_NODES * 4;
    int*            cnt     = (int*)(base + off);            off += (size_t)N_NODES * 4;
    int*            row_ptr = (int*)(base + off);            off += 200016;
    int*            col     = (int*)(base + off);            off += (size_t)N_EDGES * 4;
    unsigned short* partial = (unsigned short*)(base + off); off += (size_t)NCHUNK * NRANGE * RSPAN * 2;  // 6.4MB
    unsigned short* wfh     = (unsigned short*)(base + off); off += (size_t)N_LAYERS * 16384 * 2;
    int*            bsum    = (int*)(base + off);            off += 1024;
    unsigned*       gstart  = (unsigned*)(base + off);       off += 2048;
    unsigned*       gend    = (unsigned*)(base + off);       off += 2048;

    k_prep_hist<<<NHB + 40 + 1024, 256, 0, stream>>>(x, Ws, xb, wfh, dstp,
                                                     partial, gstart, gend);
    k_colsum<<<NB, 256, 0, stream>>>(partial, bat, cnt, dinv, gstart, gend, bsum);
    k_rowptr<<<NB, 256, 0, stream>>>(cnt, bsum, row_ptr);
    // fill (col only) + layer-0 GEMM in one dispatch
    k_fill_gemm<<<NHB + BGEMM, 256, 0, stream>>>(srcp, dstp, partial, row_ptr,
                                                 col, xb, wfh, tB);

    const int BAGG = 3125;                       // 3125 * 16 quarter-waves = 50000

    unsigned short* houts[N_LAYERS] = { hB0, hB1, hB0, hB1, hB0 };
    k_agg_t<<<BAGG, 256, 0, stream>>>(tB, bs, hB0, dinv, row_ptr, col);
    const unsigned short* hin = hB0;
    for (int l = 1; l < N_LAYERS; ++l) {
        unsigned short* ho = houts[l];
        k_gemm_pool<<<BGEMM + N_GRAPHS, 256, 0, stream>>>(hin, wfh + (size_t)l * 16384,
                                                          tB, gstart, gend, outp, l - 1);
        k_agg_t<<<BAGG, 256, 0, stream>>>(tB, bs + (size_t)l * DIM, ho,
                                          dinv, row_ptr, col);
        hin = ho;
    }
    k_pool_b<<<N_GRAPHS, 512, 0, stream>>>(houts[4], gstart, gend, outp, 4);
}

// Round 18
// 256.091 us; speedup vs baseline: 1.0844x; 1.0844x over previous
//
#include <hip/hip_runtime.h>

#define N_NODES  50000
#define N_EDGES  600000
#define DIM      128
#define N_LAYERS 5
#define N_GRAPHS 512
#define NB       ((N_NODES + 255) / 256)   // 196
#define NRANGE   16
#define RSPAN    3125                      // 16 * 3125 = 50000
#define NCHUNK   64
#define ESPAN    9375                      // 64 * 9375 = 600000
#define NHB      (NRANGE * NCHUNK)         // 1024 hist/fill blocks
#define BGEMM    782                       // 64-row MFMA tiles

typedef __attribute__((ext_vector_type(8))) short short8;
typedef __attribute__((ext_vector_type(4))) float f32x4;

// bf16 <-> f32 bit helpers (RNE)
__device__ __forceinline__ unsigned short f2b(float f) {
    unsigned u = __float_as_uint(f);
    return (unsigned short)((u + 0x7FFFu + ((u >> 16) & 1u)) >> 16);
}
__device__ __forceinline__ float b2f(short s) {
    return __uint_as_float(((unsigned)(unsigned short)s) << 16);
}
__device__ __forceinline__ float4 b2f4(ushort4 u) {
    float4 c;
    c.x = __uint_as_float((unsigned)u.x << 16);
    c.y = __uint_as_float((unsigned)u.y << 16);
    c.z = __uint_as_float((unsigned)u.z << 16);
    c.w = __uint_as_float((unsigned)u.w << 16);
    return c;
}

// ---------------------------------------------------------------- GEMM body (shared)
// t(bf16) = hin(bf16) @ W_hi, one 64-row tile. Whl = 32KB fragment-ordered LDS.
// Layouts (guide §3): A row=lane&15, k=(lane>>4)*8+j; B col=lane&15, same k;
// C/D col=lane&15, row=(lane>>4)*4+reg.
__device__ __forceinline__ void gemm_tile(const unsigned short* __restrict__ hin,
                                          const unsigned short* __restrict__ wh,
                                          unsigned short* __restrict__ t,
                                          short* Whl, int tile, int tid) {
    const int wv   = tid >> 6;
    const int lane = tid & 63;
    const int rb   = tile * 64;

    {   // stage W_hi (2048 float4, coalesced, 8/thread)
        const float4* GH = (const float4*)wh;
        float4* SH = (float4*)Whl;
#pragma unroll
        for (int i = 0; i < 8; ++i) SH[tid + i * 256] = GH[tid + i * 256];
    }

    int rowA = rb + wv * 16 + (lane & 15);
    if (rowA > N_NODES - 1) rowA = N_NODES - 1;   // clamp loads; store guarded
    const unsigned short* Ab = hin + (size_t)rowA * DIM + (lane >> 4) * 8;
    short8 a[4];
#pragma unroll
    for (int ks = 0; ks < 4; ++ks)
        a[ks] = *(const short8*)(Ab + ks * 32);

    __syncthreads();   // W staged

    f32x4 acc[8] = {};
    const short8* WH = (const short8*)Whl;
#pragma unroll
    for (int nt = 0; nt < 8; ++nt) {
#pragma unroll
        for (int ks = 0; ks < 4; ++ks) {
            short8 bh = WH[(nt * 4 + ks) * 64 + lane];
            acc[nt] = __builtin_amdgcn_mfma_f32_16x16x32_bf16(a[ks], bh, acc[nt], 0, 0, 0);
        }
    }

    const int rowC = rb + wv * 16 + (lane >> 4) * 4;
    const int cl   = lane & 15;
#pragma unroll
    for (int nt = 0; nt < 8; ++nt) {
#pragma unroll
        for (int r = 0; r < 4; ++r) {
            int row = rowC + r;
            if (row < N_NODES)
                t[(size_t)row * DIM + nt * 16 + cl] = f2b(acc[nt][r]);
        }
    }
}

// ---------------------------------------------------------------- preprocess
// Fused dispatch 1: blocks [0,NHB) LDS-histogram; [NHB,NHB+40) W->bf16 frag;
// [NHB+40, +1024) x->bf16. All independent.
__global__ __launch_bounds__(256) void k_prep_hist(const float* __restrict__ x,
                                                   const float* __restrict__ W,
                                                   unsigned short* __restrict__ xb,
                                                   unsigned short* __restrict__ wh,
                                                   const int* __restrict__ dst,
                                                   unsigned short* __restrict__ partial,
                                                   unsigned* __restrict__ gstart,
                                                   unsigned* __restrict__ gend) {
    __shared__ int histo[RSPAN];
    if (blockIdx.x < NHB) {
        const int r  = blockIdx.x & 15;
        const int c  = blockIdx.x >> 4;
        const int lo = r * RSPAN;
        for (int i = threadIdx.x; i < RSPAN; i += 256) histo[i] = 0;
        if (blockIdx.x == 0) {
            for (int i = threadIdx.x; i < N_GRAPHS; i += 256) { gstart[i] = 0u; gend[i] = 0u; }
        }
        __syncthreads();
        const int e0 = c * ESPAN;
        for (int e = e0 + threadIdx.x; e < e0 + ESPAN; e += 256) {
            int d = dst[e] - lo;
            if ((unsigned)d < (unsigned)RSPAN) atomicAdd(&histo[d], 1);
        }
        __syncthreads();
        unsigned short* p = partial + (size_t)(c * NRANGE + r) * RSPAN;
        for (int i = threadIdx.x; i < RSPAN; i += 256) p[i] = (unsigned short)histo[i];
    } else if (blockIdx.x < NHB + 40) {
        // W[5][128][128] f32 -> fragment order: ((nt*4+ks)*64+lane)*8+j,
        // k = ks*32 + (lane>>4)*8 + j, n = nt*16 + (lane&15)
        int t = (blockIdx.x - NHB) * 256 + threadIdx.x;   // < 10240 exactly
        int lane = t & 63;
        int ks   = (t >> 6) & 3;
        int nt   = (t >> 8) & 7;
        int l    = t >> 11;
        int n  = nt * 16 + (lane & 15);
        int kb = ks * 32 + (lane >> 4) * 8;
        size_t obase = (size_t)t * 8;
#pragma unroll
        for (int j = 0; j < 8; ++j) {
            float f = W[(size_t)l * 16384 + (kb + j) * DIM + n];
            wh[obase + j] = f2b(f);
        }
    } else {
        const int total = N_NODES * 32;                   // float4 groups
        for (int t = (blockIdx.x - NHB - 40) * 256 + threadIdx.x; t < total;
             t += 1024 * 256) {
            float4 v = ((const float4*)x)[t];
            ushort4 o;
            o.x = f2b(v.x); o.y = f2b(v.y); o.z = f2b(v.z); o.w = f2b(v.w);
            ((ushort4*)xb)[t] = o;
        }
    }
}

// per node: cnt = sum over chunks (in-place exclusive chunk-prefix), dinv,
// graph ranges (sorted-batch boundaries), fused per-block sum -> bsum.
__global__ __launch_bounds__(256) void k_colsum(unsigned short* __restrict__ partial,
                                                const int* __restrict__ batch,
                                                int* __restrict__ cnt,
                                                float* __restrict__ dinv,
                                                unsigned* __restrict__ gstart,
                                                unsigned* __restrict__ gend,
                                                int* __restrict__ bsum) {
    __shared__ int ws[4];
    int i = blockIdx.x * 256 + threadIdx.x;
    const int inb = (i < N_NODES);
    int sum = 0;
    if (inb) {
        int r  = i / RSPAN;
        int li = i - r * RSPAN;
#pragma unroll 4
        for (int c = 0; c < NCHUNK; ++c) {
            unsigned short* p = partial + (size_t)(c * NRANGE + r) * RSPAN + li;
            int v = *p;
            *p = (unsigned short)sum;     // exclusive prefix over chunks (fits u16)
            sum += v;
        }
    }
    int v = sum;
#pragma unroll
    for (int o = 32; o > 0; o >>= 1) v += __shfl_down(v, o, 64);
    if ((threadIdx.x & 63) == 0) ws[threadIdx.x >> 6] = v;
    __syncthreads();
    if (threadIdx.x == 0) bsum[blockIdx.x] = ws[0] + ws[1] + ws[2] + ws[3];

    if (inb) {
        cnt[i]  = sum;
        dinv[i] = rsqrtf((float)(sum + 1));   // +1 self-loop
        int b = batch[i];
        if (i == 0) gstart[b] = 0u;
        else {
            int pb = batch[i - 1];
            if (b != pb) { gstart[b] = (unsigned)i; gend[pb] = (unsigned)i; }
        }
        if (i == N_NODES - 1) gend[b] = (unsigned)N_NODES;
    }
}

// row_ptr: each block redundantly scans the 196 block sums (cheap), then
// scans its own 256 cnt values. Replaces the separate k_scan_bsum dispatch.
__global__ __launch_bounds__(256) void k_rowptr(const int* __restrict__ cnt,
                                                const int* __restrict__ bsum,
                                                int* __restrict__ row_ptr) {
    __shared__ int sb[256];
    __shared__ int s[256];
    int t = threadIdx.x;
    int bv = (t < NB) ? bsum[t] : 0;
    sb[t] = bv;
    __syncthreads();
    for (int o = 1; o < 256; o <<= 1) {
        int u = (t >= o) ? sb[t - o] : 0;
        __syncthreads();
        sb[t] += u;
        __syncthreads();
    }
    int i = blockIdx.x * 256 + t;
    int v = (i < N_NODES) ? cnt[i] : 0;
    s[t] = v;
    __syncthreads();
    for (int o = 1; o < 256; o <<= 1) {
        int u = (t >= o) ? s[t - o] : 0;
        __syncthreads();
        s[t] += u;
        __syncthreads();
    }
    int boffblk = sb[blockIdx.x] - bsum[blockIdx.x];   // exclusive block offset
    int excl = boffblk + s[t] - v;
    if (i < N_NODES)       row_ptr[i] = excl;
    else if (i == N_NODES) row_ptr[N_NODES] = excl;
}

// Fused dispatch 4: blocks [0,NHB) CSR fill (LDS cursor, no global atomics);
// blocks [NHB, NHB+BGEMM) layer-0 GEMM (independent of CSR -> hides under fill).
__global__ __launch_bounds__(256, 2) void k_fill_gemm(const int* __restrict__ src,
                                                      const int* __restrict__ dst,
                                                      const unsigned short* __restrict__ partial,
                                                      const int* __restrict__ row_ptr,
                                                      const float* __restrict__ dinv,
                                                      int* __restrict__ col,
                                                      float* __restrict__ wnorm,
                                                      const unsigned short* __restrict__ hin,
                                                      const unsigned short* __restrict__ wh,
                                                      unsigned short* __restrict__ t) {
    __shared__ char smem[32768];
    const int tid = threadIdx.x;
    if (blockIdx.x < NHB) {
        int*   lcur = (int*)smem;               // 12.5KB
        float* dl   = (float*)(smem + 12512);   // 12.5KB
        const int r  = blockIdx.x & 15;
        const int c  = blockIdx.x >> 4;
        const int lo = r * RSPAN;
        const unsigned short* pp = partial + (size_t)(c * NRANGE + r) * RSPAN;
        for (int i = tid; i < RSPAN; i += 256) {
            lcur[i] = row_ptr[lo + i] + (int)pp[i];
            dl[i]   = dinv[lo + i];
        }
        __syncthreads();
        const int e0 = c * ESPAN;
        for (int e = e0 + tid; e < e0 + ESPAN; e += 256) {
            int d = dst[e] - lo;
            int s = src[e];
            if ((unsigned)d < (unsigned)RSPAN) {
                int pos = atomicAdd(&lcur[d], 1);
                col[pos]   = s;
                wnorm[pos] = dinv[s] * dl[d];
            }
        }
    } else {
        gemm_tile(hin, wh, t, (short*)smem, blockIdx.x - NHB, tid);
    }
}

// ---------------------------------------------------------------- transform (MFMA) + hidden pool
__global__ __launch_bounds__(256, 2) void k_gemm_pool(const unsigned short* __restrict__ hin,
                                                      const unsigned short* __restrict__ wh,
                                                      unsigned short* __restrict__ t,
                                                      const unsigned* __restrict__ gstart,
                                                      const unsigned* __restrict__ gend,
                                                      float* __restrict__ out,
                                                      int poolLayer) {
    __shared__ char smem[32768];
    const int tid = threadIdx.x;
    if (blockIdx.x < BGEMM) {
        gemm_tile(hin, wh, t, (short*)smem, blockIdx.x, tid);
    } else {
        float4* red = (float4*)smem;   // [8][32]
        const int g    = blockIdx.x - BGEMM;
        const int slot = tid & 31;
        const int way  = tid >> 5;
        unsigned s = gstart[g], e = gend[g];
        float4 sum = make_float4(0.f, 0.f, 0.f, 0.f);
        for (unsigned i = s + way; i < e; i += 8) {
            float4 v = b2f4(((const ushort4*)hin)[(size_t)i * 32 + slot]);
            sum.x += v.x; sum.y += v.y; sum.z += v.z; sum.w += v.w;
        }
        red[way * 32 + slot] = sum;
        __syncthreads();
        if (tid < 32) {
            float4 tt = red[slot];
#pragma unroll
            for (int wy = 1; wy < 8; ++wy) {
                float4 v = red[wy * 32 + slot];
                tt.x += v.x; tt.y += v.y; tt.z += v.z; tt.w += v.w;
            }
            *(float4*)&out[(size_t)g * (N_LAYERS * DIM) + poolLayer * DIM + slot * 4] = tt;
        }
    }
}

// ---------------------------------------------------------------- aggregation
// hout(bf16) = relu( gather(t, bf16) + bias ). Quarter-wave per node: 16
// lanes x short8 (16B) = 256B row; 4 nodes/wave -> 32 gathers in flight/wave.
// Per-output-element summation order identical to the half-wave version.
__global__ __launch_bounds__(256) void k_agg_t(const unsigned short* __restrict__ t,
                                               const float* __restrict__ bias,
                                               unsigned short* __restrict__ hout,
                                               const float* __restrict__ dinv,
                                               const int* __restrict__ row_ptr,
                                               const int* __restrict__ col,
                                               const float* __restrict__ wnorm) {
    const int node = blockIdx.x * 16 + (threadIdx.x >> 4);   // 3125*16 = 50000
    const int slot = threadIdx.x & 15;
    const short8* __restrict__ t8 = (const short8*)t + slot;

    float di = dinv[node];
    float dii = di * di;
    short8 v = t8[(size_t)node * 16];
    float acc[8];
#pragma unroll
    for (int j = 0; j < 8; ++j) acc[j] = b2f(v[j]) * dii;    // self-loop

    int e0 = row_ptr[node], e1 = row_ptr[node + 1];
    const int last = e1 - 1;
    for (int e = e0; e < e1; e += 8) {
        int jj[8]; float wt[8];
#pragma unroll
        for (int i = 0; i < 8; ++i) {
            int ee = e + i;
            int cl = (ee <= last) ? ee : last;
            jj[i] = col[cl];
            wt[i] = (ee <= last) ? wnorm[cl] : 0.f;
        }
        short8 u[8];
#pragma unroll
        for (int i = 0; i < 8; ++i) u[i] = t8[(size_t)jj[i] * 16];
#pragma unroll
        for (int i = 0; i < 8; ++i)
#pragma unroll
            for (int j = 0; j < 8; ++j)
                acc[j] += b2f(u[i][j]) * wt[i];
    }

    const float* bp = bias + slot * 8;
    short8 o;
#pragma unroll
    for (int j = 0; j < 8; ++j)
        o[j] = (short)f2b(fmaxf(acc[j] + bp[j], 0.f));
    ((short8*)hout)[(size_t)node * 16 + slot] = o;
}

// ---------------------------------------------------------------- standalone pool (last layer)
__global__ __launch_bounds__(512) void k_pool_b(const unsigned short* __restrict__ h,
                                                const unsigned* __restrict__ gstart,
                                                const unsigned* __restrict__ gend,
                                                float* __restrict__ out, int layer) {
    __shared__ float4 red[16][32];
    int g    = blockIdx.x;
    int slot = threadIdx.x & 31;
    int way  = threadIdx.x >> 5;
    unsigned s = gstart[g], e = gend[g];
    float4 sum = make_float4(0.f, 0.f, 0.f, 0.f);
    for (unsigned i = s + way; i < e; i += 16) {
        float4 v = b2f4(((const ushort4*)h)[(size_t)i * 32 + slot]);
        sum.x += v.x; sum.y += v.y; sum.z += v.z; sum.w += v.w;
    }
    red[way][slot] = sum;
    __syncthreads();
    if (threadIdx.x < 32) {
        float4 t = red[0][slot];
#pragma unroll
        for (int wy = 1; wy < 16; ++wy) {
            float4 v = red[wy][slot];
            t.x += v.x; t.y += v.y; t.z += v.z; t.w += v.w;
        }
        *(float4*)&out[(size_t)g * (N_LAYERS * DIM) + layer * DIM + slot * 4] = t;
    }
}

// ---------------------------------------------------------------- launch

extern "C" void kernel_launch(void* const* d_in, const int* in_sizes, int n_in,
                              void* d_out, int out_size, void* d_ws, size_t ws_size,
                              hipStream_t stream) {
    const float* x    = (const float*)d_in[0];
    const int*   ei   = (const int*)d_in[1];
    const int*   bat  = (const int*)d_in[2];
    const float* Ws   = (const float*)d_in[3];
    const float* bs   = (const float*)d_in[4];
    float*       outp = (float*)d_out;

    const int* srcp = ei;
    const int* dstp = ei + N_EDGES;

    char* base = (char*)d_ws;
    size_t off = 0;
    unsigned short* xb      = (unsigned short*)(base + off); off += (size_t)N_NODES * DIM * 2;
    unsigned short* tB      = (unsigned short*)(base + off); off += (size_t)N_NODES * DIM * 2;
    unsigned short* hB0     = (unsigned short*)(base + off); off += (size_t)N_NODES * DIM * 2;
    unsigned short* hB1     = (unsigned short*)(base + off); off += (size_t)N_NODES * DIM * 2;
    float*          dinv    = (float*)(base + off);          off += (size_t)N_NODES * 4;
    int*            cnt     = (int*)(base + off);            off += (size_t)N_NODES * 4;
    int*            row_ptr = (int*)(base + off);            off += 200016;
    int*            col     = (int*)(base + off);            off += (size_t)N_EDGES * 4;
    float*          wnorm   = (float*)(base + off);          off += (size_t)N_EDGES * 4;
    unsigned short* partial = (unsigned short*)(base + off); off += (size_t)NCHUNK * NRANGE * RSPAN * 2;  // 6.4MB
    unsigned short* wfh     = (unsigned short*)(base + off); off += (size_t)N_LAYERS * 16384 * 2;
    int*            bsum    = (int*)(base + off);            off += 1024;
    unsigned*       gstart  = (unsigned*)(base + off);       off += 2048;
    unsigned*       gend    = (unsigned*)(base + off);       off += 2048;

    k_prep_hist<<<NHB + 40 + 1024, 256, 0, stream>>>(x, Ws, xb, wfh, dstp,
                                                     partial, gstart, gend);
    k_colsum<<<NB, 256, 0, stream>>>(partial, bat, cnt, dinv, gstart, gend, bsum);
    k_rowptr<<<NB, 256, 0, stream>>>(cnt, bsum, row_ptr);
    // fill + layer-0 GEMM (independent of CSR) in one dispatch
    k_fill_gemm<<<NHB + BGEMM, 256, 0, stream>>>(srcp, dstp, partial, row_ptr, dinv,
                                                 col, wnorm, xb, wfh, tB);

    const int BAGG = 3125;                       // 3125 * 16 quarter-waves = 50000

    unsigned short* houts[N_LAYERS] = { hB0, hB1, hB0, hB1, hB0 };
    k_agg_t<<<BAGG, 256, 0, stream>>>(tB, bs, hB0, dinv, row_ptr, col, wnorm);
    const unsigned short* hin = hB0;
    for (int l = 1; l < N_LAYERS; ++l) {
        unsigned short* ho = houts[l];
        k_gemm_pool<<<BGEMM + N_GRAPHS, 256, 0, stream>>>(hin, wfh + (size_t)l * 16384,
                                                          tB, gstart, gend, outp, l - 1);
        k_agg_t<<<BAGG, 256, 0, stream>>>(tB, bs + (size_t)l * DIM, ho,
                                          dinv, row_ptr, col, wnorm);
        hin = ho;
    }
    k_pool_b<<<N_GRAPHS, 512, 0, stream>>>(houts[4], gstart, gend, outp, 4);
}